// Round 7
// baseline (256.018 us; speedup 1.0000x reference)
//
#include <hip/hip_runtime.h>
#include <cstdint>
#include <cstddef>

// ---------------------------------------------------------------------------
// GraphConvBlock, fp32 in/out. B=32 S=512 D=512 H=8 HD=64, ADJ=512.
// adj_s mask (adj_s==0) can never fire -> adj/sem_W/sem_b dead.
// No fp32 MFMA on CDNA4 -> bf16 intermediates/weights, fp32 accum.
// GEMM (round 7): 128x128 tile, BK=64, 512 threads (8 waves, 2x4 wave grid,
// 4x2 acc tiles/wave) -> 16-24 waves/CU resident vs 8-12 at 256 thr.
// Both operands via global_load_lds width-16; XOR chunk-swizzle (0 bank
// conflicts, verified round 6).
// Attention: rank-1 scores e_ij = leaky(src_i+dst_j); P fragments generated
// per-lane in registers; only PV uses MFMA (round-6 version, unchanged).
// ---------------------------------------------------------------------------

typedef __bf16 bfx8 __attribute__((ext_vector_type(8)));
typedef float v4f __attribute__((ext_vector_type(4)));
typedef unsigned short u16x8 __attribute__((ext_vector_type(8)));

__device__ __forceinline__ float bf2f(unsigned short h) {
    unsigned int u = ((unsigned int)h) << 16;
    return __builtin_bit_cast(float, u);
}
__device__ __forceinline__ unsigned short f2bf(float x) {
    unsigned int u = __builtin_bit_cast(unsigned int, x);
    unsigned int r = (u + 0x7fffu + ((u >> 16) & 1u)) >> 16;  // RNE
    return (unsigned short)r;
}
__device__ __forceinline__ u16x8 load8cvt(const float* p) {
    float4 a = *(const float4*)p;
    float4 b = *(const float4*)(p + 4);
    u16x8 r;
    r[0] = f2bf(a.x); r[1] = f2bf(a.y); r[2] = f2bf(a.z); r[3] = f2bf(a.w);
    r[4] = f2bf(b.x); r[5] = f2bf(b.y); r[6] = f2bf(b.z); r[7] = f2bf(b.w);
    return r;
}
__device__ __forceinline__ void gl_lds16(const unsigned short* g, unsigned short* l) {
    __builtin_amdgcn_global_load_lds((const __attribute__((address_space(1))) void*)g,
                                     (__attribute__((address_space(3))) void*)l, 16, 0, 0);
}

// fp32 -> bf16 conversion pass (8 elems/thread)
__global__ __launch_bounds__(256) void cvt_kernel(const float* __restrict__ in,
                                                  unsigned short* __restrict__ out) {
    const int id = blockIdx.x * 256 + threadIdx.x;
    *(u16x8*)(out + (size_t)id * 8) = load8cvt(in + (size_t)id * 8);
}

// ---------------------------------------------------------------------------
// GEMM: C[M,N] = A[M,K] @ W[N,K]^T + bias. A,W bf16; bias fp32; C bf16/fp32.
// 128x128 tile, BK=64, 512 thr (2x4 waves; each wave 4mi x 2ni tiles of 16).
// Staging: 2 gl_lds rounds per operand; thread t -> row sr=t>>3 (+64 for
// round 2), swizzled col ((t&7)^(sr&7))*8. LDS[row][ch] = global chunk
// ch^(row&7); read side applies the same XOR (row&7 == mrow&7).
// blockIdx.x = m-block: same-A blocks 128 apart -> same XCD -> L2 A reuse.
// EPI: 0 = bias, 1 = bias + exact GELU.
// ---------------------------------------------------------------------------
#define BM 128
#define BN 128
#define BK 64

template <int EPI, typename CT>
__global__ __launch_bounds__(512, 6) void gemm_bt(
    const unsigned short* __restrict__ A, const unsigned short* __restrict__ Bw,
    const float* __restrict__ bias, CT* __restrict__ C,
    int M, int N, int K) {
    __shared__ unsigned short sA[BM * BK];  // 16 KB
    __shared__ unsigned short sB[BN * BK];  // 16 KB
    const int t = threadIdx.x;   // 0..511
    const int lane = t & 63;
    const int w = t >> 6;        // 0..7
    const int wm = w >> 2, wn = w & 3;
    const int m0 = blockIdx.x * BM, n0 = blockIdx.y * BN;
    const int mrow = lane & 15, kq = lane >> 4;

    v4f acc[4][2];
#pragma unroll
    for (int i = 0; i < 4; i++)
#pragma unroll
        for (int j = 0; j < 2; j++) acc[i][j] = (v4f)(0.0f);

    const int sr = t >> 3;                       // 0..63
    const int sc = ((t & 7) ^ (sr & 7)) * 8;     // swizzled global col
    const unsigned short* pA0 = A + (size_t)(m0 + sr) * K + sc;
    const unsigned short* pA1 = pA0 + (size_t)64 * K;
    const unsigned short* pB0 = Bw + (size_t)(n0 + sr) * K + sc;
    const unsigned short* pB1 = pB0 + (size_t)64 * K;

    for (int k0 = 0; k0 < K; k0 += BK) {
        gl_lds16(pA0 + k0, &sA[t * 8]);
        gl_lds16(pA1 + k0, &sA[(512 + t) * 8]);
        gl_lds16(pB0 + k0, &sB[t * 8]);
        gl_lds16(pB1 + k0, &sB[(512 + t) * 8]);
        __syncthreads();
#pragma unroll
        for (int kh = 0; kh < 2; kh++) {
            const int ch = (kh * 4 + kq) ^ (mrow & 7);
            bfx8 af[4], bfr[2];
#pragma unroll
            for (int mi = 0; mi < 4; mi++) {
                const int r = wm * 64 + mi * 16 + mrow;
                af[mi] = __builtin_bit_cast(bfx8, *(const u16x8*)&sA[r * BK + ch * 8]);
            }
#pragma unroll
            for (int ni = 0; ni < 2; ni++) {
                const int r = wn * 32 + ni * 16 + mrow;
                bfr[ni] = __builtin_bit_cast(bfx8, *(const u16x8*)&sB[r * BK + ch * 8]);
            }
#pragma unroll
            for (int mi = 0; mi < 4; mi++)
#pragma unroll
                for (int ni = 0; ni < 2; ni++)
                    acc[mi][ni] = __builtin_amdgcn_mfma_f32_16x16x32_bf16(af[mi], bfr[ni], acc[mi][ni], 0, 0, 0);
        }
        __syncthreads();
    }
    // epilogue: D row=(lane>>4)*4+r, col=lane&15 (m89-verified C/D layout)
#pragma unroll
    for (int ni = 0; ni < 2; ni++) {
        const int col = n0 + wn * 32 + ni * 16 + mrow;
        const float bv = bias[col];
#pragma unroll
        for (int mi = 0; mi < 4; mi++) {
#pragma unroll
            for (int r = 0; r < 4; r++) {
                const int row = m0 + wm * 64 + mi * 16 + kq * 4 + r;
                float val = acc[mi][ni][r] + bv;
                if (EPI == 1) val = 0.5f * val * (1.0f + erff(val * 0.70710678118654752f));
                if constexpr (__is_same(CT, float)) C[(size_t)row * N + col] = val;
                else C[(size_t)row * N + col] = f2bf(val);
            }
        }
    }
}

// ---------------------------------------------------------------------------
// src/dst: per (b,head,i), dot h[b,i,head*64+0..63] with a_w[:64] / a_w[64:].
// ---------------------------------------------------------------------------
__global__ __launch_bounds__(256) void srcdst_kernel(
    const unsigned short* __restrict__ hbuf, const float* __restrict__ aw,
    float* __restrict__ src, float* __restrict__ dst) {
    const int id = blockIdx.x * 256 + threadIdx.x;  // (b,head,i) flat
    const int i = id & 511;
    const int bh = id >> 9;
    const int head = bh & 7, b = bh >> 3;
    const unsigned short* hp = hbuf + ((size_t)(b * 512 + i)) * 512 + head * 64;
    float s = 0.f, d = 0.f;
#pragma unroll
    for (int c = 0; c < 8; c++) {
        u16x8 hv = *(const u16x8*)(hp + c * 8);
        float4 a0 = *(const float4*)(aw + c * 8);
        float4 a1 = *(const float4*)(aw + c * 8 + 4);
        float4 d0 = *(const float4*)(aw + 64 + c * 8);
        float4 d1 = *(const float4*)(aw + 64 + c * 8 + 4);
        float av[8] = {a0.x, a0.y, a0.z, a0.w, a1.x, a1.y, a1.z, a1.w};
        float dv[8] = {d0.x, d0.y, d0.z, d0.w, d1.x, d1.y, d1.z, d1.w};
#pragma unroll
        for (int j = 0; j < 8; j++) {
            float x = bf2f(hv[j]);
            s += x * av[j];
            d += x * dv[j];
        }
    }
    src[id] = s;
    dst[id] = d;
}

// ---------------------------------------------------------------------------
// Attention: grid = 512 (2 blocks per (b,head), 256 rows each), 512 threads
// (8 waves; each wave 32 rows = 2 MFMA row-groups). Round-6 version.
// ---------------------------------------------------------------------------
__global__ __launch_bounds__(512, 4) void attn_kernel(
    const unsigned short* __restrict__ hbuf, const float* __restrict__ srcg,
    const float* __restrict__ dstg, unsigned short* __restrict__ aout) {
    __shared__ unsigned short Ht[64 * 512];  // 64 KB static

    const int t = threadIdx.x, lane = t & 63, w = t >> 6;  // w in 0..7
    const int bq = blockIdx.x;          // 0..511
    const int bh = bq >> 1, half = bq & 1;
    const int b = bh >> 3, head = bh & 7;
    const size_t hbase = (size_t)(b * 512) * 512 + head * 64;

    {
        const int d = lane;
        const int sw = d & 7;
#pragma unroll
        for (int jc = 0; jc < 8; ++jc) {
            const int j0 = w * 64 + jc * 8;
            u16x8 pack;
#pragma unroll
            for (int jj = 0; jj < 8; jj++)
                pack[jj] = hbuf[hbase + (size_t)(j0 + jj) * 512 + d];
            const int gj = (j0 >> 3) ^ sw;
            *(u16x8*)&Ht[d * 512 + gj * 8] = pack;
        }
    }
    __syncthreads();

    float dmax = -1e30f;
#pragma unroll
    for (int q = 0; q < 8; q++) dmax = fmaxf(dmax, dstg[bh * 512 + q * 64 + lane]);
#pragma unroll
    for (int off = 32; off >= 1; off >>= 1) dmax = fmaxf(dmax, __shfl_xor(dmax, off, 64));

    const int mrow = lane & 15, kq = lane >> 4;
    const int rbase = half * 256 + w * 32;  // this wave's 32 rows

    const float si0 = srcg[bh * 512 + rbase + mrow];
    const float si1 = srcg[bh * 512 + rbase + 16 + mrow];
    const float e00 = si0 + dmax, e01 = si1 + dmax;
    const float mi0 = fmaxf(e00, 0.2f * e00);
    const float mi1 = fmaxf(e01, 0.2f * e01);

    float sum0 = 0.f, sum1 = 0.f;
    v4f acc0[4], acc1[4];
#pragma unroll
    for (int nt = 0; nt < 4; nt++) { acc0[nt] = (v4f)(0.0f); acc1[nt] = (v4f)(0.0f); }

#pragma unroll 2
    for (int ks = 0; ks < 16; ++ks) {
        const int j0 = ks * 32 + kq * 8;
        float4 d0 = *(const float4*)&dstg[bh * 512 + j0];
        float4 d1 = *(const float4*)&dstg[bh * 512 + j0 + 4];
        float dj[8] = {d0.x, d0.y, d0.z, d0.w, d1.x, d1.y, d1.z, d1.w};
        bfx8 bfr[4];
#pragma unroll
        for (int nt = 0; nt < 4; nt++) {
            const int dd = nt * 16 + mrow;
            const int gj = (ks * 4 + kq) ^ (dd & 7);
            bfr[nt] = __builtin_bit_cast(bfx8, *(const u16x8*)&Ht[dd * 512 + gj * 8]);
        }
        bfx8 a0, a1;
#pragma unroll
        for (int jj = 0; jj < 8; jj++) {
            const float t0 = si0 + dj[jj];
            const float l0 = fmaxf(t0, 0.2f * t0);
            const float p0 = __expf(l0 - mi0);
            sum0 += p0;
            a0[jj] = (__bf16)p0;
            const float t1 = si1 + dj[jj];
            const float l1 = fmaxf(t1, 0.2f * t1);
            const float p1 = __expf(l1 - mi1);
            sum1 += p1;
            a1[jj] = (__bf16)p1;
        }
#pragma unroll
        for (int nt = 0; nt < 4; nt++) {
            acc0[nt] = __builtin_amdgcn_mfma_f32_16x16x32_bf16(a0, bfr[nt], acc0[nt], 0, 0, 0);
            acc1[nt] = __builtin_amdgcn_mfma_f32_16x16x32_bf16(a1, bfr[nt], acc1[nt], 0, 0, 0);
        }
    }
    sum0 += __shfl_xor(sum0, 16, 64);
    sum0 += __shfl_xor(sum0, 32, 64);
    sum1 += __shfl_xor(sum1, 16, 64);
    sum1 += __shfl_xor(sum1, 32, 64);
#pragma unroll
    for (int r = 0; r < 4; r++) {
        const float inv0 = 1.0f / __shfl(sum0, kq * 4 + r, 64);
        const float inv1 = 1.0f / __shfl(sum1, kq * 4 + r, 64);
        const int row0 = b * 512 + rbase + kq * 4 + r;
        const int row1 = row0 + 16;
#pragma unroll
        for (int nt = 0; nt < 4; nt++) {
            const int col = head * 64 + nt * 16 + mrow;
            aout[(size_t)row0 * 512 + col] = f2bf(acc0[nt][r] * inv0);
            aout[(size_t)row1 * 512 + col] = f2bf(acc1[nt][r] * inv1);
        }
    }
}

// ---------------------------------------------------------------------------
// LayerNorm: out = (v-mean)/sqrt(var+1e-5)*g + b, v = xin + res. 1 wave/row.
// Typed loads/stores; safe in-place when out aliases xin.
// ---------------------------------------------------------------------------
template <typename T>
__device__ __forceinline__ void loadf8(const T* p, float* v) {
    if constexpr (__is_same(T, float)) {
        float4 a = *(const float4*)p;
        float4 b = *(const float4*)(p + 4);
        v[0] = a.x; v[1] = a.y; v[2] = a.z; v[3] = a.w;
        v[4] = b.x; v[5] = b.y; v[6] = b.z; v[7] = b.w;
    } else {
        u16x8 h = *(const u16x8*)p;
#pragma unroll
        for (int j = 0; j < 8; j++) v[j] = bf2f(h[j]);
    }
}

template <typename XT, typename RT, typename OT>
__global__ __launch_bounds__(256) void ln_kernel(
    const XT* __restrict__ xin, const RT* __restrict__ res,
    const float* __restrict__ gg, const float* __restrict__ bb,
    OT* __restrict__ out) {
    const int row = blockIdx.x * 4 + (threadIdx.x >> 6);
    const int lane = threadIdx.x & 63;
    const size_t base = (size_t)row * 512 + lane * 8;
    float xv[8], rv[8], v[8];
    loadf8(xin + base, xv);
    loadf8(res + base, rv);
    float s1 = 0.f, s2 = 0.f;
#pragma unroll
    for (int j = 0; j < 8; j++) {
        v[j] = xv[j] + rv[j];
        s1 += v[j];
        s2 += v[j] * v[j];
    }
#pragma unroll
    for (int off = 1; off < 64; off <<= 1) {
        s1 += __shfl_xor(s1, off, 64);
        s2 += __shfl_xor(s2, off, 64);
    }
    const float mean = s1 * (1.0f / 512.0f);
    const float var = s2 * (1.0f / 512.0f) - mean * mean;
    const float rstd = rsqrtf(var + 1e-5f);
    float gv[8], bv[8];
    loadf8(gg + lane * 8, gv);
    loadf8(bb + lane * 8, bv);
    float o[8];
#pragma unroll
    for (int j = 0; j < 8; j++) o[j] = (v[j] - mean) * rstd * gv[j] + bv[j];
    if constexpr (__is_same(OT, float)) {
        *(float4*)(out + base) = make_float4(o[0], o[1], o[2], o[3]);
        *(float4*)(out + base + 4) = make_float4(o[4], o[5], o[6], o[7]);
    } else {
        u16x8 ov;
#pragma unroll
        for (int j = 0; j < 8; j++) ov[j] = f2bf(o[j]);
        *(u16x8*)(out + base) = ov;
    }
}

// ---------------------------------------------------------------------------
extern "C" void kernel_launch(void* const* d_in, const int* in_sizes, int n_in,
                              void* d_out, int out_size, void* d_ws, size_t ws_size,
                              hipStream_t stream) {
    const float* x   = (const float*)d_in[0];
    // d_in[1] adj, d_in[5] sem_W, d_in[6] sem_b: dead (mask can't fire)
    const float* wW  = (const float*)d_in[2];
    const float* wb  = (const float*)d_in[3];
    const float* aw  = (const float*)d_in[4];
    const float* f1W = (const float*)d_in[7];
    const float* f1b = (const float*)d_in[8];
    const float* f2W = (const float*)d_in[9];
    const float* f2b = (const float*)d_in[10];
    const float* g1  = (const float*)d_in[11];
    const float* b1  = (const float*)d_in[12];
    const float* g2  = (const float*)d_in[13];
    const float* b2  = (const float*)d_in[14];
    float* out = (float*)d_out;

    // Workspace (<= 56.6 MiB used). Lifetimes:
    //   [0,16M):  xb bf16 (steps 0..4: GEMM1 A + LN1 residual)
    //   [16,32M): hb (1-3)
    //   [32,48M): aoutb (3) -> y bf16 (4-7, in-place LN1)
    //   [0,32M):  gbuf (5-6; xb,hb dead after LN1)
    //   [48,..):  src/dst fp32 (2-3); wWb/f1Wb/f2Wb bf16 weights
    // z = d_out fp32 (step 6); LN2 in-place on d_out.
    char* ws = (char*)d_ws;
    unsigned short* xb    = (unsigned short*)(ws);
    unsigned short* hb    = (unsigned short*)(ws + 16777216);
    unsigned short* aoutb = (unsigned short*)(ws + 33554432);
    unsigned short* y     = (unsigned short*)(ws + 33554432);  // in-place LN1
    unsigned short* gbuf  = (unsigned short*)(ws);
    float* src            = (float*)(ws + 50331648);
    float* dst            = (float*)(ws + 50331648 + 524288);
    unsigned short* wWb   = (unsigned short*)(ws + 52428800);
    unsigned short* f1Wb  = (unsigned short*)(ws + 53477376);
    unsigned short* f2Wb  = (unsigned short*)(ws + 55574528);

    (void)in_sizes; (void)n_in; (void)out_size; (void)ws_size;

    dim3 blk(256);
    // 0) bf16 conversions: x (16M elems), wW (256K), f1W (512K), f2W (512K)
    cvt_kernel<<<dim3(4096), blk, 0, stream>>>(x, xb);
    cvt_kernel<<<dim3(128), blk, 0, stream>>>(wW, wWb);
    cvt_kernel<<<dim3(256), blk, 0, stream>>>(f1W, f1Wb);
    cvt_kernel<<<dim3(256), blk, 0, stream>>>(f2W, f2Wb);
    // 1) h = x @ w_W^T + w_b        (M=16384, N=512, K=512)
    gemm_bt<0, unsigned short><<<dim3(128, 4), dim3(512), 0, stream>>>(xb, wWb, wb, hb, 16384, 512, 512);
    // 2) src/dst head dots
    srcdst_kernel<<<dim3(512), blk, 0, stream>>>(hb, aw, src, dst);
    // 3) attention -> aoutb (back in (b, s, h*64+d) layout)
    attn_kernel<<<dim3(512), dim3(512), 0, stream>>>(hb, src, dst, aoutb);
    // 4) y = LN1(attn_out + x)      (bf16 residual xb; in-place on aoutb)
    ln_kernel<unsigned short, unsigned short, unsigned short>
        <<<dim3(4096), blk, 0, stream>>>(aoutb, xb, g1, b1, y);
    // 5) g = gelu(y @ ff1_W^T + ff1_b)   (N=1024, K=512)
    gemm_bt<1, unsigned short><<<dim3(128, 8), dim3(512), 0, stream>>>(y, f1Wb, f1b, gbuf, 16384, 1024, 512);
    // 6) z = g @ ff2_W^T + ff2_b         (N=512, K=1024) -> fp32 into d_out
    gemm_bt<0, float><<<dim3(128, 4), dim3(512), 0, stream>>>(gbuf, f2Wb, f2b, out, 16384, 512, 1024);
    // 7) out = LN2(z + y)  (in-place on d_out)
    ln_kernel<float, unsigned short, float>
        <<<dim3(4096), blk, 0, stream>>>(out, y, g2, b2, out);
}

// Round 8
// 248.235 us; speedup vs baseline: 1.0314x; 1.0314x over previous
//
#include <hip/hip_runtime.h>
#include <cstdint>
#include <cstddef>

// ---------------------------------------------------------------------------
// GraphConvBlock, fp32 in/out. B=32 S=512 D=512 H=8 HD=64, ADJ=512.
// adj_s mask (adj_s==0) can never fire -> adj/sem_W/sem_b dead.
// No fp32 MFMA on CDNA4 -> bf16 intermediates/weights, fp32 accum.
// GEMM (round 8): 128x64 tile, BK=64, 256 thr (2x2 waves, 4x2 acc tiles).
// Rationale: latency streams per CU = resident BLOCKS (barriers sync whole
// blocks; r6/r7 A/B showed FLOPs scale with blocks/CU, not waves/block).
// 128x64 doubles the grid: steps 1/6 -> 4 blocks/CU, step 5 -> 6 (LDS cap).
// Both operands via global_load_lds width-16; XOR chunk-swizzle (0 bank
// conflicts, verified round 6).
// Attention: rank-1 scores e_ij = leaky(src_i+dst_j); P fragments generated
// per-lane in registers; only PV uses MFMA (round-6 version, unchanged).
// ---------------------------------------------------------------------------

typedef __bf16 bfx8 __attribute__((ext_vector_type(8)));
typedef float v4f __attribute__((ext_vector_type(4)));
typedef unsigned short u16x8 __attribute__((ext_vector_type(8)));

__device__ __forceinline__ float bf2f(unsigned short h) {
    unsigned int u = ((unsigned int)h) << 16;
    return __builtin_bit_cast(float, u);
}
__device__ __forceinline__ unsigned short f2bf(float x) {
    unsigned int u = __builtin_bit_cast(unsigned int, x);
    unsigned int r = (u + 0x7fffu + ((u >> 16) & 1u)) >> 16;  // RNE
    return (unsigned short)r;
}
__device__ __forceinline__ u16x8 load8cvt(const float* p) {
    float4 a = *(const float4*)p;
    float4 b = *(const float4*)(p + 4);
    u16x8 r;
    r[0] = f2bf(a.x); r[1] = f2bf(a.y); r[2] = f2bf(a.z); r[3] = f2bf(a.w);
    r[4] = f2bf(b.x); r[5] = f2bf(b.y); r[6] = f2bf(b.z); r[7] = f2bf(b.w);
    return r;
}
__device__ __forceinline__ void gl_lds16(const unsigned short* g, unsigned short* l) {
    __builtin_amdgcn_global_load_lds((const __attribute__((address_space(1))) void*)g,
                                     (__attribute__((address_space(3))) void*)l, 16, 0, 0);
}

// fp32 -> bf16 conversion pass (8 elems/thread)
__global__ __launch_bounds__(256) void cvt_kernel(const float* __restrict__ in,
                                                  unsigned short* __restrict__ out) {
    const int id = blockIdx.x * 256 + threadIdx.x;
    *(u16x8*)(out + (size_t)id * 8) = load8cvt(in + (size_t)id * 8);
}

// ---------------------------------------------------------------------------
// GEMM: C[M,N] = A[M,K] @ W[N,K]^T + bias. A,W bf16; bias fp32; C bf16/fp32.
// 128x64 tile, BK=64, 256 thr (2x2 waves; each wave 4mi x 2ni tiles of 16).
// LDS 24 KB/block -> up to 6 blocks/CU. Staging: rounds of 32 rows; thread t
// covers row c*32 + (t>>3), swizzled col ((t&7)^(row&7))*8; LDS[row][ch]
// holds global chunk ch^(row&7); read side applies the same XOR.
// blockIdx.x = m-block: same-A blocks 128 apart -> same XCD -> L2 A reuse.
// EPI: 0 = bias, 1 = bias + exact GELU.
// ---------------------------------------------------------------------------
#define BM 128
#define BN 64
#define BK 64

template <int EPI, typename CT>
__global__ __launch_bounds__(256, 6) void gemm_bt(
    const unsigned short* __restrict__ A, const unsigned short* __restrict__ Bw,
    const float* __restrict__ bias, CT* __restrict__ C,
    int M, int N, int K) {
    __shared__ unsigned short sA[BM * BK];  // 16 KB
    __shared__ unsigned short sB[BN * BK];  // 8 KB
    const int t = threadIdx.x;   // 0..255
    const int lane = t & 63;
    const int w = t >> 6;        // 0..3
    const int wm = w >> 1, wn = w & 1;
    const int m0 = blockIdx.x * BM, n0 = blockIdx.y * BN;
    const int mrow = lane & 15, kq = lane >> 4;

    v4f acc[4][2];
#pragma unroll
    for (int i = 0; i < 4; i++)
#pragma unroll
        for (int j = 0; j < 2; j++) acc[i][j] = (v4f)(0.0f);

    const int sr = t >> 3;                       // 0..31
    const int sc = ((t & 7) ^ (sr & 7)) * 8;     // swizzled global col
    const unsigned short* pA[4];
#pragma unroll
    for (int c = 0; c < 4; c++) pA[c] = A + (size_t)(m0 + c * 32 + sr) * K + sc;
    const unsigned short* pB[2];
#pragma unroll
    for (int c = 0; c < 2; c++) pB[c] = Bw + (size_t)(n0 + c * 32 + sr) * K + sc;

    for (int k0 = 0; k0 < K; k0 += BK) {
#pragma unroll
        for (int c = 0; c < 4; c++) gl_lds16(pA[c] + k0, &sA[(c * 256 + t) * 8]);
#pragma unroll
        for (int c = 0; c < 2; c++) gl_lds16(pB[c] + k0, &sB[(c * 256 + t) * 8]);
        __syncthreads();
#pragma unroll
        for (int kh = 0; kh < 2; kh++) {
            const int ch = (kh * 4 + kq) ^ (mrow & 7);
            bfx8 af[4], bfr[2];
#pragma unroll
            for (int mi = 0; mi < 4; mi++) {
                const int r = wm * 64 + mi * 16 + mrow;
                af[mi] = __builtin_bit_cast(bfx8, *(const u16x8*)&sA[r * BK + ch * 8]);
            }
#pragma unroll
            for (int ni = 0; ni < 2; ni++) {
                const int r = wn * 32 + ni * 16 + mrow;
                bfr[ni] = __builtin_bit_cast(bfx8, *(const u16x8*)&sB[r * BK + ch * 8]);
            }
#pragma unroll
            for (int mi = 0; mi < 4; mi++)
#pragma unroll
                for (int ni = 0; ni < 2; ni++)
                    acc[mi][ni] = __builtin_amdgcn_mfma_f32_16x16x32_bf16(af[mi], bfr[ni], acc[mi][ni], 0, 0, 0);
        }
        __syncthreads();
    }
    // epilogue: D row=(lane>>4)*4+r, col=lane&15 (m89-verified C/D layout)
#pragma unroll
    for (int ni = 0; ni < 2; ni++) {
        const int col = n0 + wn * 32 + ni * 16 + mrow;
        const float bv = bias[col];
#pragma unroll
        for (int mi = 0; mi < 4; mi++) {
#pragma unroll
            for (int r = 0; r < 4; r++) {
                const int row = m0 + wm * 64 + mi * 16 + kq * 4 + r;
                float val = acc[mi][ni][r] + bv;
                if (EPI == 1) val = 0.5f * val * (1.0f + erff(val * 0.70710678118654752f));
                if constexpr (__is_same(CT, float)) C[(size_t)row * N + col] = val;
                else C[(size_t)row * N + col] = f2bf(val);
            }
        }
    }
}

// ---------------------------------------------------------------------------
// src/dst: per (b,head,i), dot h[b,i,head*64+0..63] with a_w[:64] / a_w[64:].
// ---------------------------------------------------------------------------
__global__ __launch_bounds__(256) void srcdst_kernel(
    const unsigned short* __restrict__ hbuf, const float* __restrict__ aw,
    float* __restrict__ src, float* __restrict__ dst) {
    const int id = blockIdx.x * 256 + threadIdx.x;  // (b,head,i) flat
    const int i = id & 511;
    const int bh = id >> 9;
    const int head = bh & 7, b = bh >> 3;
    const unsigned short* hp = hbuf + ((size_t)(b * 512 + i)) * 512 + head * 64;
    float s = 0.f, d = 0.f;
#pragma unroll
    for (int c = 0; c < 8; c++) {
        u16x8 hv = *(const u16x8*)(hp + c * 8);
        float4 a0 = *(const float4*)(aw + c * 8);
        float4 a1 = *(const float4*)(aw + c * 8 + 4);
        float4 d0 = *(const float4*)(aw + 64 + c * 8);
        float4 d1 = *(const float4*)(aw + 64 + c * 8 + 4);
        float av[8] = {a0.x, a0.y, a0.z, a0.w, a1.x, a1.y, a1.z, a1.w};
        float dv[8] = {d0.x, d0.y, d0.z, d0.w, d1.x, d1.y, d1.z, d1.w};
#pragma unroll
        for (int j = 0; j < 8; j++) {
            float x = bf2f(hv[j]);
            s += x * av[j];
            d += x * dv[j];
        }
    }
    src[id] = s;
    dst[id] = d;
}

// ---------------------------------------------------------------------------
// Attention: grid = 512 (2 blocks per (b,head), 256 rows each), 512 threads
// (8 waves; each wave 32 rows = 2 MFMA row-groups). Round-6 version.
// ---------------------------------------------------------------------------
__global__ __launch_bounds__(512, 4) void attn_kernel(
    const unsigned short* __restrict__ hbuf, const float* __restrict__ srcg,
    const float* __restrict__ dstg, unsigned short* __restrict__ aout) {
    __shared__ unsigned short Ht[64 * 512];  // 64 KB static

    const int t = threadIdx.x, lane = t & 63, w = t >> 6;  // w in 0..7
    const int bq = blockIdx.x;          // 0..511
    const int bh = bq >> 1, half = bq & 1;
    const int b = bh >> 3, head = bh & 7;
    const size_t hbase = (size_t)(b * 512) * 512 + head * 64;

    {
        const int d = lane;
        const int sw = d & 7;
#pragma unroll
        for (int jc = 0; jc < 8; ++jc) {
            const int j0 = w * 64 + jc * 8;
            u16x8 pack;
#pragma unroll
            for (int jj = 0; jj < 8; jj++)
                pack[jj] = hbuf[hbase + (size_t)(j0 + jj) * 512 + d];
            const int gj = (j0 >> 3) ^ sw;
            *(u16x8*)&Ht[d * 512 + gj * 8] = pack;
        }
    }
    __syncthreads();

    float dmax = -1e30f;
#pragma unroll
    for (int q = 0; q < 8; q++) dmax = fmaxf(dmax, dstg[bh * 512 + q * 64 + lane]);
#pragma unroll
    for (int off = 32; off >= 1; off >>= 1) dmax = fmaxf(dmax, __shfl_xor(dmax, off, 64));

    const int mrow = lane & 15, kq = lane >> 4;
    const int rbase = half * 256 + w * 32;  // this wave's 32 rows

    const float si0 = srcg[bh * 512 + rbase + mrow];
    const float si1 = srcg[bh * 512 + rbase + 16 + mrow];
    const float e00 = si0 + dmax, e01 = si1 + dmax;
    const float mi0 = fmaxf(e00, 0.2f * e00);
    const float mi1 = fmaxf(e01, 0.2f * e01);

    float sum0 = 0.f, sum1 = 0.f;
    v4f acc0[4], acc1[4];
#pragma unroll
    for (int nt = 0; nt < 4; nt++) { acc0[nt] = (v4f)(0.0f); acc1[nt] = (v4f)(0.0f); }

#pragma unroll 2
    for (int ks = 0; ks < 16; ++ks) {
        const int j0 = ks * 32 + kq * 8;
        float4 d0 = *(const float4*)&dstg[bh * 512 + j0];
        float4 d1 = *(const float4*)&dstg[bh * 512 + j0 + 4];
        float dj[8] = {d0.x, d0.y, d0.z, d0.w, d1.x, d1.y, d1.z, d1.w};
        bfx8 bfr[4];
#pragma unroll
        for (int nt = 0; nt < 4; nt++) {
            const int dd = nt * 16 + mrow;
            const int gj = (ks * 4 + kq) ^ (dd & 7);
            bfr[nt] = __builtin_bit_cast(bfx8, *(const u16x8*)&Ht[dd * 512 + gj * 8]);
        }
        bfx8 a0, a1;
#pragma unroll
        for (int jj = 0; jj < 8; jj++) {
            const float t0 = si0 + dj[jj];
            const float l0 = fmaxf(t0, 0.2f * t0);
            const float p0 = __expf(l0 - mi0);
            sum0 += p0;
            a0[jj] = (__bf16)p0;
            const float t1 = si1 + dj[jj];
            const float l1 = fmaxf(t1, 0.2f * t1);
            const float p1 = __expf(l1 - mi1);
            sum1 += p1;
            a1[jj] = (__bf16)p1;
        }
#pragma unroll
        for (int nt = 0; nt < 4; nt++) {
            acc0[nt] = __builtin_amdgcn_mfma_f32_16x16x32_bf16(a0, bfr[nt], acc0[nt], 0, 0, 0);
            acc1[nt] = __builtin_amdgcn_mfma_f32_16x16x32_bf16(a1, bfr[nt], acc1[nt], 0, 0, 0);
        }
    }
    sum0 += __shfl_xor(sum0, 16, 64);
    sum0 += __shfl_xor(sum0, 32, 64);
    sum1 += __shfl_xor(sum1, 16, 64);
    sum1 += __shfl_xor(sum1, 32, 64);
#pragma unroll
    for (int r = 0; r < 4; r++) {
        const float inv0 = 1.0f / __shfl(sum0, kq * 4 + r, 64);
        const float inv1 = 1.0f / __shfl(sum1, kq * 4 + r, 64);
        const int row0 = b * 512 + rbase + kq * 4 + r;
        const int row1 = row0 + 16;
#pragma unroll
        for (int nt = 0; nt < 4; nt++) {
            const int col = head * 64 + nt * 16 + mrow;
            aout[(size_t)row0 * 512 + col] = f2bf(acc0[nt][r] * inv0);
            aout[(size_t)row1 * 512 + col] = f2bf(acc1[nt][r] * inv1);
        }
    }
}

// ---------------------------------------------------------------------------
// LayerNorm: out = (v-mean)/sqrt(var+1e-5)*g + b, v = xin + res. 1 wave/row.
// Typed loads/stores; safe in-place when out aliases xin.
// ---------------------------------------------------------------------------
template <typename T>
__device__ __forceinline__ void loadf8(const T* p, float* v) {
    if constexpr (__is_same(T, float)) {
        float4 a = *(const float4*)p;
        float4 b = *(const float4*)(p + 4);
        v[0] = a.x; v[1] = a.y; v[2] = a.z; v[3] = a.w;
        v[4] = b.x; v[5] = b.y; v[6] = b.z; v[7] = b.w;
    } else {
        u16x8 h = *(const u16x8*)p;
#pragma unroll
        for (int j = 0; j < 8; j++) v[j] = bf2f(h[j]);
    }
}

template <typename XT, typename RT, typename OT>
__global__ __launch_bounds__(256) void ln_kernel(
    const XT* __restrict__ xin, const RT* __restrict__ res,
    const float* __restrict__ gg, const float* __restrict__ bb,
    OT* __restrict__ out) {
    const int row = blockIdx.x * 4 + (threadIdx.x >> 6);
    const int lane = threadIdx.x & 63;
    const size_t base = (size_t)row * 512 + lane * 8;
    float xv[8], rv[8], v[8];
    loadf8(xin + base, xv);
    loadf8(res + base, rv);
    float s1 = 0.f, s2 = 0.f;
#pragma unroll
    for (int j = 0; j < 8; j++) {
        v[j] = xv[j] + rv[j];
        s1 += v[j];
        s2 += v[j] * v[j];
    }
#pragma unroll
    for (int off = 1; off < 64; off <<= 1) {
        s1 += __shfl_xor(s1, off, 64);
        s2 += __shfl_xor(s2, off, 64);
    }
    const float mean = s1 * (1.0f / 512.0f);
    const float var = s2 * (1.0f / 512.0f) - mean * mean;
    const float rstd = rsqrtf(var + 1e-5f);
    float gv[8], bv[8];
    loadf8(gg + lane * 8, gv);
    loadf8(bb + lane * 8, bv);
    float o[8];
#pragma unroll
    for (int j = 0; j < 8; j++) o[j] = (v[j] - mean) * rstd * gv[j] + bv[j];
    if constexpr (__is_same(OT, float)) {
        *(float4*)(out + base) = make_float4(o[0], o[1], o[2], o[3]);
        *(float4*)(out + base + 4) = make_float4(o[4], o[5], o[6], o[7]);
    } else {
        u16x8 ov;
#pragma unroll
        for (int j = 0; j < 8; j++) ov[j] = f2bf(o[j]);
        *(u16x8*)(out + base) = ov;
    }
}

// ---------------------------------------------------------------------------
extern "C" void kernel_launch(void* const* d_in, const int* in_sizes, int n_in,
                              void* d_out, int out_size, void* d_ws, size_t ws_size,
                              hipStream_t stream) {
    const float* x   = (const float*)d_in[0];
    // d_in[1] adj, d_in[5] sem_W, d_in[6] sem_b: dead (mask can't fire)
    const float* wW  = (const float*)d_in[2];
    const float* wb  = (const float*)d_in[3];
    const float* aw  = (const float*)d_in[4];
    const float* f1W = (const float*)d_in[7];
    const float* f1b = (const float*)d_in[8];
    const float* f2W = (const float*)d_in[9];
    const float* f2b = (const float*)d_in[10];
    const float* g1  = (const float*)d_in[11];
    const float* b1  = (const float*)d_in[12];
    const float* g2  = (const float*)d_in[13];
    const float* b2  = (const float*)d_in[14];
    float* out = (float*)d_out;

    // Workspace (<= 56.6 MiB used; ws is 256 MiB per round-7 profile).
    //   [0,16M):  xb bf16 (steps 0..4: GEMM1 A + LN1 residual)
    //   [16,32M): hb (1-3)
    //   [32,48M): aoutb (3) -> y bf16 (4-7, in-place LN1)
    //   [0,32M):  gbuf (5-6; xb,hb dead after LN1)
    //   [48,..):  src/dst fp32 (2-3); wWb/f1Wb/f2Wb bf16 weights
    // z = d_out fp32 (step 6); LN2 in-place on d_out.
    char* ws = (char*)d_ws;
    unsigned short* xb    = (unsigned short*)(ws);
    unsigned short* hb    = (unsigned short*)(ws + 16777216);
    unsigned short* aoutb = (unsigned short*)(ws + 33554432);
    unsigned short* y     = (unsigned short*)(ws + 33554432);  // in-place LN1
    unsigned short* gbuf  = (unsigned short*)(ws);
    float* src            = (float*)(ws + 50331648);
    float* dst            = (float*)(ws + 50331648 + 524288);
    unsigned short* wWb   = (unsigned short*)(ws + 52428800);
    unsigned short* f1Wb  = (unsigned short*)(ws + 53477376);
    unsigned short* f2Wb  = (unsigned short*)(ws + 55574528);

    (void)in_sizes; (void)n_in; (void)out_size; (void)ws_size;

    dim3 blk(256);
    // 0) bf16 conversions: x (16M elems), wW (256K), f1W (512K), f2W (512K)
    cvt_kernel<<<dim3(4096), blk, 0, stream>>>(x, xb);
    cvt_kernel<<<dim3(128), blk, 0, stream>>>(wW, wWb);
    cvt_kernel<<<dim3(256), blk, 0, stream>>>(f1W, f1Wb);
    cvt_kernel<<<dim3(256), blk, 0, stream>>>(f2W, f2Wb);
    // 1) h = x @ w_W^T + w_b        (M=16384, N=512, K=512)  1024 blocks
    gemm_bt<0, unsigned short><<<dim3(128, 8), blk, 0, stream>>>(xb, wWb, wb, hb, 16384, 512, 512);
    // 2) src/dst head dots
    srcdst_kernel<<<dim3(512), blk, 0, stream>>>(hb, aw, src, dst);
    // 3) attention -> aoutb (back in (b, s, h*64+d) layout)
    attn_kernel<<<dim3(512), dim3(512), 0, stream>>>(hb, src, dst, aoutb);
    // 4) y = LN1(attn_out + x)      (bf16 residual xb; in-place on aoutb)
    ln_kernel<unsigned short, unsigned short, unsigned short>
        <<<dim3(4096), blk, 0, stream>>>(aoutb, xb, g1, b1, y);
    // 5) g = gelu(y @ ff1_W^T + ff1_b)   (N=1024, K=512)     2048 blocks
    gemm_bt<1, unsigned short><<<dim3(128, 16), blk, 0, stream>>>(y, f1Wb, f1b, gbuf, 16384, 1024, 512);
    // 6) z = g @ ff2_W^T + ff2_b         (N=512, K=1024)     1024 blocks
    gemm_bt<0, float><<<dim3(128, 8), blk, 0, stream>>>(gbuf, f2Wb, f2b, out, 16384, 512, 1024);
    // 7) out = LN2(z + y)  (in-place on d_out)
    ln_kernel<float, unsigned short, float>
        <<<dim3(4096), blk, 0, stream>>>(out, y, g2, b2, out);
}